// Round 2
// 821.820 us; speedup vs baseline: 1.0023x; 1.0023x over previous
//
#include <hip/hip_runtime.h>

// Haar wavedec2(level=1) + waverec2 == per-2x2-block forward+inverse Haar.
// Streaming kernel: exactly 1 read + 1 write per element (1.074 GB total).
// This revision: grid-stride @ 2048 blocks (8 blocks/CU on 256 CUs = full
// occupancy, contiguous per-round address coverage) + non-temporal hints on
// both streams (in+out = 1 GB >> 256 MiB L3, so caching is pure thrash).
// NOTE: nontemporal builtins need a clang vector type, not HIP's float4 class.

#define W 512           // last dim (cols)
#define INV_SQRT2 0.7071067811865476f

typedef float vf4 __attribute__((ext_vector_type(4)));

__global__ __launch_bounds__(256) void haar_roundtrip_kernel(
    const float* __restrict__ x, float* __restrict__ out, int total_units) {
    // unit = one 2-row x 4-col patch (two 2x2 Haar blocks), 8 floats.
    int stride = gridDim.x * blockDim.x;
    for (int idx = blockIdx.x * blockDim.x + threadIdx.x; idx < total_units;
         idx += stride) {
        // unit -> (image n, row-pair rp in [0,256), col-quad cq in [0,128))
        int cq = idx & 127;
        int rp = (idx >> 7) & 255;
        int n  = idx >> 15;

        long base = (long)n * (W * W) + (long)(rp * 2) * W + cq * 4;

        const vf4 top =
            __builtin_nontemporal_load((const vf4*)(x + base));      // row 2*rp
        const vf4 bot =
            __builtin_nontemporal_load((const vf4*)(x + base + W));  // row 2*rp+1

        vf4 otop, obot;

        // ---- block 0: (top[0], top[1], bot[0], bot[1]) ----
        {
            float a = top[0], b = top[1], c = bot[0], d = bot[1];
            // row DWT (pairs along rows axis): e=row even, o=row odd
            float lo0 = (a + c) * INV_SQRT2, lo1 = (b + d) * INV_SQRT2;
            float hi0 = (a - c) * INV_SQRT2, hi1 = (b - d) * INV_SQRT2;
            // col DWT
            float ll = (lo0 + lo1) * INV_SQRT2, lh = (lo0 - lo1) * INV_SQRT2;
            float hl = (hi0 + hi1) * INV_SQRT2, hh = (hi0 - hi1) * INV_SQRT2;
            // col IDWT
            float rlo0 = (ll + lh) * INV_SQRT2, rlo1 = (ll - lh) * INV_SQRT2;
            float rhi0 = (hl + hh) * INV_SQRT2, rhi1 = (hl - hh) * INV_SQRT2;
            // row IDWT
            otop[0] = (rlo0 + rhi0) * INV_SQRT2;
            otop[1] = (rlo1 + rhi1) * INV_SQRT2;
            obot[0] = (rlo0 - rhi0) * INV_SQRT2;
            obot[1] = (rlo1 - rhi1) * INV_SQRT2;
        }

        // ---- block 1: (top[2], top[3], bot[2], bot[3]) ----
        {
            float a = top[2], b = top[3], c = bot[2], d = bot[3];
            float lo0 = (a + c) * INV_SQRT2, lo1 = (b + d) * INV_SQRT2;
            float hi0 = (a - c) * INV_SQRT2, hi1 = (b - d) * INV_SQRT2;
            float ll = (lo0 + lo1) * INV_SQRT2, lh = (lo0 - lo1) * INV_SQRT2;
            float hl = (hi0 + hi1) * INV_SQRT2, hh = (hi0 - hi1) * INV_SQRT2;
            float rlo0 = (ll + lh) * INV_SQRT2, rlo1 = (ll - lh) * INV_SQRT2;
            float rhi0 = (hl + hh) * INV_SQRT2, rhi1 = (hl - hh) * INV_SQRT2;
            otop[2] = (rlo0 + rhi0) * INV_SQRT2;
            otop[3] = (rlo1 + rhi1) * INV_SQRT2;
            obot[2] = (rlo0 - rhi0) * INV_SQRT2;
            obot[3] = (rlo1 - rhi1) * INV_SQRT2;
        }

        __builtin_nontemporal_store(otop, (vf4*)(out + base));
        __builtin_nontemporal_store(obot, (vf4*)(out + base + W));
    }
}

extern "C" void kernel_launch(void* const* d_in, const int* in_sizes, int n_in,
                              void* d_out, int out_size, void* d_ws, size_t ws_size,
                              hipStream_t stream) {
    const float* x = (const float*)d_in[0];
    float* out = (float*)d_out;

    int total_elems = in_sizes[0];              // 16*32*512*512 = 134217728
    int total_units = total_elems / 8;          // 8 elements per unit (2x4)
    int block = 256;
    // G11: cap the grid and grid-stride. 2048 blocks = 8 blocks/CU on 256 CUs
    // -> 32 waves/CU (full occupancy); each thread walks 32 units.
    int grid = 2048;
    int max_grid = (total_units + block - 1) / block;
    if (grid > max_grid) grid = max_grid;

    haar_roundtrip_kernel<<<grid, block, 0, stream>>>(x, out, total_units);
}